// Round 1
// baseline (445.902 us; speedup 1.0000x reference)
//
#include <hip/hip_runtime.h>
#include <hip/hip_bf16.h>

// ChebyKAN: y[b,o] = sum_{i,d} T_d(tanh(x[b,i])) * W[i,o,d]
// == GEMM M=16384, N=1024, K=9216 with generated A (Chebyshev recurrence).
// fp16 MFMA, W pre-scaled by 4096 (avoids fp16 subnormals), f32 accum.

#define BATCH 16384
#define IDIM  1024
#define ODIM  1024
#define NDEG  9            // DEG+1
#define WSCALE 4096.0f
#define INV_WSCALE (1.0f/4096.0f)

typedef _Float16 f16;
typedef _Float16 f16x8 __attribute__((ext_vector_type(8)));
typedef float    f32x4 __attribute__((ext_vector_type(4)));

// ---------------- kernel 1: repack cheby_coeffs [I][O][9] f32 -> Wt [9][I/32][O][32] f16 (x4096)
__global__ __launch_bounds__(256) void wt_transform(const float* __restrict__ cc,
                                                    f16* __restrict__ wt) {
  int gid = blockIdx.x * 256 + threadIdx.x;   // 0 .. 9*32*1024-1
  int o   = gid & 1023;
  int t2  = gid >> 10;
  int ic  = t2 & 31;          // i-chunk (32 i's)
  int d   = t2 >> 5;          // 0..8
  const size_t rowbase = ((size_t)(d * 32 + ic) * 1024 + o) * 32;
#pragma unroll
  for (int u = 0; u < 4; ++u) {
    f16x8 v;
#pragma unroll
    for (int e = 0; e < 8; ++e) {
      int i = ic * 32 + u * 8 + e;
      float w = cc[((size_t)i * 1024 + o) * 9 + d] * WSCALE;
      v[e] = (f16)w;
    }
    *(f16x8*)(wt + rowbase + u * 8) = v;      // 16B contiguous store
  }
}

// ---------------- kernel 2: fused basis-gen + GEMM
// block: 256 thr = 4 waves (2x2), tile 128x128, K-step 32 (fixed d per step)
__global__ __launch_bounds__(256, 2) void cheby_gemm(const float* __restrict__ x,
                                                     const f16* __restrict__ wt,
                                                     float* __restrict__ out) {
  __shared__ f16 bbuf[2][4096];               // 2 x (128 o x 32 k) fp16 = 16 KB

  const int tid  = threadIdx.x;
  const int wid  = tid >> 6;
  const int lane = tid & 63;
  const int r    = lane & 15;                 // A: m-row / B: n-col within frag
  const int g    = lane >> 4;                 // k-group (8 elems)
  const int wr   = wid >> 1, wc = wid & 1;
  const int mrow = blockIdx.x >> 3;           // 128 row-blocks
  const int ncol = blockIdx.x & 7;            // 8 col-blocks
  const int m0   = mrow * 128 + wr * 64;
  const int n0   = ncol * 128 + wc * 64;
  const int nc128 = ncol * 128;

  // stage B-tile for K-step (cn-th i-chunk, degree dn) into bbuf[buf]
  auto stage = [&](int cn, int dn, int buf) {
    const f16* src = wt + ((size_t)(dn * 32 + cn) * 1024 + nc128) * 32;
    __builtin_amdgcn_global_load_lds(
        (const __attribute__((address_space(1))) unsigned*)(src + tid * 8),
        (__attribute__((address_space(3))) unsigned*)(&bbuf[buf][wid * 512]),
        16, 0, 0);
    __builtin_amdgcn_global_load_lds(
        (const __attribute__((address_space(1))) unsigned*)(src + 2048 + tid * 8),
        (__attribute__((address_space(3))) unsigned*)(&bbuf[buf][wid * 512 + 2048]),
        16, 0, 0);
  };

  f32x4 acc[4][4];
#pragma unroll
  for (int a = 0; a < 4; ++a)
#pragma unroll
    for (int b = 0; b < 4; ++b) acc[a][b] = (f32x4){0.f, 0.f, 0.f, 0.f};

  float tt[4][8], P0[4][8], P1[4][8], P2[4][8];
  f32x4 xf[4][2];

  // prologue
  stage(0, 0, 0);
  __syncthreads();

  for (int c = 0; c < 32; ++c) {
    // issue x loads for this chunk; latency hides under the d=0 (T_0 = 1) step
#pragma unroll
    for (int fm = 0; fm < 4; ++fm) {
      const float* p = x + (size_t)(m0 + fm * 16 + r) * 1024 + c * 32 + g * 8;
      xf[fm][0] = *(const f32x4*)p;
      xf[fm][1] = *(const f32x4*)(p + 4);
    }

#pragma unroll
    for (int d = 0; d < 9; ++d) {
      const int s = c * 9 + d;
      const int cur = s & 1;
      if (s < 287) stage(d == 8 ? c + 1 : c, d == 8 ? 0 : d + 1, cur ^ 1);

      if (d == 1) {
        // t = tanh(x) = 1 - 2/(e^{2x}+1)
#pragma unroll
        for (int fm = 0; fm < 4; ++fm)
#pragma unroll
          for (int e = 0; e < 8; ++e) {
            float xx = (e < 4) ? xf[fm][0][e] : xf[fm][1][e - 4];
            tt[fm][e] = 1.f - 2.f * __builtin_amdgcn_rcpf(__expf(2.f * xx) + 1.f);
          }
      }

      // A fragment (per m-frag, 8 fp16 along k=i_local)
      f16x8 af[4];
#define CHEB_STEP(DST, M1, M2EXPR)                                         \
  _Pragma("unroll") for (int fm = 0; fm < 4; ++fm) {                       \
    _Pragma("unroll") for (int e = 0; e < 8; ++e) {                        \
      float vn = __builtin_fmaf(2.f * tt[fm][e], M1[fm][e], -(M2EXPR));    \
      DST[fm][e] = vn;                                                     \
      af[fm][e] = (f16)vn;                                                 \
    }                                                                      \
  }
      if (d == 0) {
#pragma unroll
        for (int fm = 0; fm < 4; ++fm)
#pragma unroll
          for (int e = 0; e < 8; ++e) af[fm][e] = (f16)1.0f;
      } else if (d == 1) {
#pragma unroll
        for (int fm = 0; fm < 4; ++fm)
#pragma unroll
          for (int e = 0; e < 8; ++e) af[fm][e] = (f16)tt[fm][e];
      } else if (d == 2) { CHEB_STEP(P0, tt, 1.0f) }
      else if (d == 3) { CHEB_STEP(P1, P0, tt[fm][e]) }
      else if (d == 4) { CHEB_STEP(P2, P1, P0[fm][e]) }
      else if (d == 5) { CHEB_STEP(P0, P2, P1[fm][e]) }
      else if (d == 6) { CHEB_STEP(P1, P0, P2[fm][e]) }
      else if (d == 7) { CHEB_STEP(P2, P1, P0[fm][e]) }
      else             { CHEB_STEP(P0, P2, P1[fm][e]) }
#undef CHEB_STEP

      // B fragments from LDS (rows 64B apart -> bank-uniform, no swizzle needed)
      f16x8 bf[4];
#pragma unroll
      for (int fn = 0; fn < 4; ++fn) {
        int rowb = wc * 64 + fn * 16 + r;
        bf[fn] = *(const f16x8*)&bbuf[cur][rowb * 32 + g * 8];
      }

#pragma unroll
      for (int fm = 0; fm < 4; ++fm)
#pragma unroll
        for (int fn = 0; fn < 4; ++fn)
          acc[fm][fn] = __builtin_amdgcn_mfma_f32_16x16x32_f16(af[fm], bf[fn],
                                                               acc[fm][fn], 0, 0, 0);
      __syncthreads();
    }
  }

  // epilogue: C/D mapping col = lane&15, row = (lane>>4)*4 + j (verified m89)
#pragma unroll
  for (int fm = 0; fm < 4; ++fm)
#pragma unroll
    for (int fn = 0; fn < 4; ++fn)
#pragma unroll
      for (int j = 0; j < 4; ++j) {
        int row = m0 + fm * 16 + g * 4 + j;
        int col = n0 + fn * 16 + r;
        out[(size_t)row * 1024 + col] = acc[fm][fn][j] * INV_WSCALE;
      }
}

extern "C" void kernel_launch(void* const* d_in, const int* in_sizes, int n_in,
                              void* d_out, int out_size, void* d_ws, size_t ws_size,
                              hipStream_t stream) {
  const float* x  = (const float*)d_in[0];
  const float* cc = (const float*)d_in[1];
  f16*  wt  = (f16*)d_ws;                 // needs 9*32*1024*32*2 = 18,874,368 B
  float* out = (float*)d_out;

  hipLaunchKernelGGL(wt_transform, dim3(1152), dim3(256), 0, stream, cc, wt);
  hipLaunchKernelGGL(cheby_gemm, dim3(1024), dim3(256), 0, stream, x, wt, out);
}

// Round 2
// 386.875 us; speedup vs baseline: 1.1526x; 1.1526x over previous
//
#include <hip/hip_runtime.h>
#include <hip/hip_bf16.h>

// ChebyKAN: y[b,o] = sum_{i,d} T_d(tanh(x[b,i])) * W[i,o,d]
// GEMM M=16384, N=1024, K=9216 with generated A (packed-fp16 Chebyshev recurrence).
// R2: LDS slot-swizzle (kills 8-way bank conflict), pk_fma_f16 basis gen,
//     counted-vmcnt + raw s_barrier (no per-step vmcnt(0) drain), 3 LDS bufs.

#define WSCALE 4096.0f
#define INV_WSCALE (1.0f/4096.0f)

typedef _Float16 f16;
typedef _Float16 f16x8 __attribute__((ext_vector_type(8)));
typedef float    f32x4 __attribute__((ext_vector_type(4)));

// ---- kernel 1: repack cc [I][O][9] f32 -> wt [9][I/32][O][32] f16 (x4096),
//      with the 16B-slot XOR swizzle baked in: wt slot u of row o holds
//      k-group (u ^ ((o>>1)&3)). GEMM reads slot g^((r>>1)&3) to get group g.
__global__ __launch_bounds__(256) void wt_transform(const float* __restrict__ cc,
                                                    f16* __restrict__ wt) {
  int gid = blockIdx.x * 256 + threadIdx.x;   // 9*32*1024 threads
  int o   = gid & 1023;
  int t2  = gid >> 10;
  int ic  = t2 & 31;          // i-chunk (32 i's)
  int d   = t2 >> 5;          // 0..8
  int f   = (o >> 1) & 3;     // row swizzle key
  const size_t rowbase = ((size_t)(d * 32 + ic) * 1024 + o) * 32;
#pragma unroll
  for (int u = 0; u < 4; ++u) {
    int kg = u ^ f;           // k-group stored at slot u
    f16x8 v;
#pragma unroll
    for (int e = 0; e < 8; ++e) {
      int i = ic * 32 + kg * 8 + e;
      v[e] = (f16)(cc[((size_t)i * 1024 + o) * 9 + d] * WSCALE);
    }
    *(f16x8*)(wt + rowbase + u * 8) = v;
  }
}

// ---- kernel 2: fused basis-gen + GEMM
// 256 thr = 4 waves (2x2), tile 128x128, K-step 32 (one degree per step).
__global__ __launch_bounds__(256, 2) void cheby_gemm(const float* __restrict__ x,
                                                     const f16* __restrict__ wt,
                                                     float* __restrict__ out) {
  __shared__ f16 bbuf[3][4096];               // 3 x (128 o x 32 k) f16 = 24 KB

  const int tid  = threadIdx.x;
  const int wid  = tid >> 6;
  const int lane = tid & 63;
  const int r    = lane & 15;
  const int g    = lane >> 4;
  const int wr   = wid >> 1, wc = wid & 1;
  const int mrow = blockIdx.x >> 3;
  const int ncol = blockIdx.x & 7;            // == blockIdx.x % 8 -> same-ncol on same XCD (wt L2-resident)
  const int m0   = mrow * 128 + wr * 64;
  const int n0   = ncol * 128 + wc * 64;
  const int nc128 = ncol * 128;
  const int slotsw = g ^ ((r >> 1) & 3);      // swizzled 16B slot for B reads

  auto stage = [&](int cn, int dn, int buf) {
    const f16* src = wt + ((size_t)(dn * 32 + cn) * 1024 + nc128) * 32;
    __builtin_amdgcn_global_load_lds(
        (const __attribute__((address_space(1))) unsigned*)(src + tid * 8),
        (__attribute__((address_space(3))) unsigned*)(&bbuf[buf][wid * 512]),
        16, 0, 0);
    __builtin_amdgcn_global_load_lds(
        (const __attribute__((address_space(1))) unsigned*)(src + 2048 + tid * 8),
        (__attribute__((address_space(3))) unsigned*)(&bbuf[buf][wid * 512 + 2048]),
        16, 0, 0);
  };

  f32x4 acc[4][4];
#pragma unroll
  for (int a = 0; a < 4; ++a)
#pragma unroll
    for (int b = 0; b < 4; ++b) acc[a][b] = (f32x4){0.f, 0.f, 0.f, 0.f};

  const f16x8 ones = {(f16)1, (f16)1, (f16)1, (f16)1, (f16)1, (f16)1, (f16)1, (f16)1};
  f16x8 Tm1[4], Tm2[4], t2two[4];
  f32x4 xf[4][2];

  // prologue: steps 0 and 1 staged; loop waits vmcnt(2) -> step 0 ready
  stage(0, 0, 0);
  stage(0, 1, 1);

  for (int c = 0; c < 32; ++c) {
#pragma unroll
    for (int d = 0; d < 9; ++d) {
      // counted wait: stage(s) retired iff <= (instrs issued after it) remain.
      // stage(s+1) (2 instrs) is always after stage(s) while s<287.
      if (d == 8) {
        if (c == 31) asm volatile("s_waitcnt vmcnt(0)" ::: "memory");
        else         asm volatile("s_waitcnt vmcnt(2)" ::: "memory");
      } else {
        asm volatile("s_waitcnt vmcnt(2)" ::: "memory");
      }
      __builtin_amdgcn_s_barrier();
      asm volatile("" ::: "memory");

      // prefetch step s+2 (buf (d+2)%3, compile-time since 9c+d == d mod 3)
      if (d <= 6)            stage(c, d + 2, (d + 2) % 3);
      else if (c != 31) {
        if (d == 7)          stage(c + 1, 0, 0);
        else                 stage(c + 1, 1, 1);
      }

      if (d == 0) {
        // issue x loads for this chunk; consumed by tanh at d==1
#pragma unroll
        for (int fm = 0; fm < 4; ++fm) {
          const float* p = x + (size_t)(m0 + fm * 16 + r) * 1024 + c * 32 + g * 8;
          xf[fm][0] = *(const f32x4*)p;
          xf[fm][1] = *(const f32x4*)(p + 4);
        }
      }

      // A fragment: Chebyshev recurrence in packed fp16
      f16x8 af[4];
      if (d == 0) {
#pragma unroll
        for (int fm = 0; fm < 4; ++fm) af[fm] = ones;
      } else if (d == 1) {
#pragma unroll
        for (int fm = 0; fm < 4; ++fm) {
          f16x8 h;
#pragma unroll
          for (int e = 0; e < 8; ++e) {
            float xx = (e < 4) ? xf[fm][0][e] : xf[fm][1][e - 4];
            float tv = 1.f - 2.f * __builtin_amdgcn_rcpf(__expf(2.f * xx) + 1.f);
            h[e] = (f16)tv;
          }
          af[fm]    = h;
          Tm1[fm]   = h;
          Tm2[fm]   = ones;
          t2two[fm] = h + h;   // exact (x2)
        }
      } else {
#pragma unroll
        for (int fm = 0; fm < 4; ++fm) {
          f16x8 tn = __builtin_elementwise_fma(t2two[fm], Tm1[fm], -Tm2[fm]);
          af[fm]  = tn;
          Tm2[fm] = Tm1[fm];
          Tm1[fm] = tn;
        }
      }

      // B fragments (swizzled slot -> conflict-free ds_read_b128)
      f16x8 bf[4];
      const f16* bb = bbuf[d % 3];
#pragma unroll
      for (int fn = 0; fn < 4; ++fn) {
        int rowb = wc * 64 + fn * 16 + r;
        bf[fn] = *(const f16x8*)&bb[rowb * 32 + slotsw * 8];
      }

#pragma unroll
      for (int fm = 0; fm < 4; ++fm)
#pragma unroll
        for (int fn = 0; fn < 4; ++fn)
          acc[fm][fn] = __builtin_amdgcn_mfma_f32_16x16x32_f16(af[fm], bf[fn],
                                                               acc[fm][fn], 0, 0, 0);
    }
  }

  // epilogue: C/D map col = lane&15, row = (lane>>4)*4 + j (m89-verified)
#pragma unroll
  for (int fm = 0; fm < 4; ++fm)
#pragma unroll
    for (int fn = 0; fn < 4; ++fn)
#pragma unroll
      for (int j = 0; j < 4; ++j) {
        int row = m0 + fm * 16 + g * 4 + j;
        int col = n0 + fn * 16 + r;
        out[(size_t)row * 1024 + col] = acc[fm][fn][j] * INV_WSCALE;
      }
}

extern "C" void kernel_launch(void* const* d_in, const int* in_sizes, int n_in,
                              void* d_out, int out_size, void* d_ws, size_t ws_size,
                              hipStream_t stream) {
  const float* x  = (const float*)d_in[0];
  const float* cc = (const float*)d_in[1];
  f16*   wt  = (f16*)d_ws;                // 9*32*1024*32*2 = 18,874,368 B
  float* out = (float*)d_out;

  hipLaunchKernelGGL(wt_transform, dim3(1152), dim3(256), 0, stream, cc, wt);
  hipLaunchKernelGGL(cheby_gemm, dim3(1024), dim3(256), 0, stream, x, wt, out);
}